// Round 9
// baseline (188.536 us; speedup 1.0000x reference)
//
#include <hip/hip_runtime.h>
#include <hip/hip_bf16.h>

typedef __bf16 bf16_t;
typedef __bf16 bf16x8 __attribute__((ext_vector_type(8)));
typedef __bf16 bf16x4 __attribute__((ext_vector_type(4)));
typedef float  f32x4  __attribute__((ext_vector_type(4)));

#define SEQ    2048
#define BATCH  2
#define NHEAD  16
#define HDIM   64
#define DMODEL 1024
#define WIN    256
// 0.125 (1/sqrt(64)) * log2(e): folded into Q so softmax exp is one v_exp_f32
#define QSCALE 0.1803368801111244f

// async global->LDS, 16B per lane (dest = wave-uniform base + lane*16).
__device__ __forceinline__ void async_load16(const void* g, void* l) {
    __builtin_amdgcn_global_load_lds(
        (const __attribute__((address_space(1))) char*)(uintptr_t)g,
        (__attribute__((address_space(3))) char*)(uintptr_t)l, 16, 0, 0);
}

// ---------------------------------------------------------------------------
// Prep: z<4 -> transpose+cast W_z into Wt[z][n][k]; z>=4 -> cast x to bf16.
// ---------------------------------------------------------------------------
__global__ void prep_kernel(const float* __restrict__ x,
                            const float* __restrict__ Wq, const float* __restrict__ Wk,
                            const float* __restrict__ Wv, const float* __restrict__ Wo,
                            bf16_t* __restrict__ xb, bf16_t* __restrict__ Wt) {
    __shared__ float tile[32][33];
    const int z = blockIdx.z;
    const int tx = threadIdx.x, ty = threadIdx.y;
    if (z < 4) {
        const float* W = (z == 0) ? Wq : (z == 1) ? Wk : (z == 2) ? Wv : Wo;
        bf16_t* out = Wt + (size_t)z * DMODEL * DMODEL;
        int k0 = blockIdx.y * 32, n0 = blockIdx.x * 32;
#pragma unroll
        for (int i = 0; i < 4; i++)
            tile[ty + i * 8][tx] = W[(size_t)(k0 + ty + i * 8) * DMODEL + n0 + tx];
        __syncthreads();
#pragma unroll
        for (int i = 0; i < 4; i++)
            out[(size_t)(n0 + ty + i * 8) * DMODEL + k0 + tx] = (bf16_t)tile[tx][ty + i * 8];
    } else {
        int blk = (z - 4) * 1024 + blockIdx.y * 32 + blockIdx.x;
        int i = blk * 256 + ty * 32 + tx;          // 4096*256 = 1M float4s exact
        float4 v = ((const float4*)x)[i];
        bf16x4 o;
        o[0] = (bf16_t)v.x; o[1] = (bf16_t)v.y; o[2] = (bf16_t)v.z; o[3] = (bf16_t)v.w;
        ((bf16x4*)xb)[i] = o;
    }
}

// ---------------------------------------------------------------------------
// GEMM: C = A * Bt^T, 128x128 tile, both operands staged in LDS via
// swizzled global_load_lds (XOR chunk swizzle -> 0 bank conflicts).
// 1D grid, XCD n-strip swizzle (id&7).
// EPI 0: QKV epilogue; sel block-uniform. Q (QSCALE) and K -> [B,H,S,64];
//   V -> TRANSPOSED [B,H,64,S] via in-LDS 128x128 transpose (reuses staging).
// EPI 1: Out = acc + bo (fp32).
// ---------------------------------------------------------------------------
template <int EPI>
__global__ __launch_bounds__(256) void gemm_bt_kernel(
    const bf16_t* __restrict__ A, const bf16_t* __restrict__ Bt,
    bf16_t* __restrict__ Qb, bf16_t* __restrict__ Kb, bf16_t* __restrict__ Vt,
    float* __restrict__ Out, const float* __restrict__ bo, int K, int nPer) {
    __shared__ __attribute__((aligned(16))) bf16_t smem[2 * 128 * 64];
    bf16_t* As = smem;
    bf16_t* Bs = smem + 128 * 64;
    const int tid = threadIdx.x;
    const int wave = tid >> 6, lane = tid & 63, quad = lane >> 4, l15 = lane & 15;
    const int wm = wave >> 1, wn = wave & 1;
    const int id = blockIdx.x, xcd = id & 7, t = id >> 3;
    const int m0 = (t / nPer) * 128, n0 = (xcd * nPer + t % nPer) * 128;

    f32x4 acc[4][4] = {};

    for (int kt = 0; kt < K; kt += 64) {
#pragma unroll
        for (int i = 0; i < 4; i++) {
            int v = tid + i * 256;
            int row = v >> 3, c = (v & 7) ^ (row & 7);
            async_load16(A + (size_t)(m0 + row) * K + kt + c * 8, (char*)As + (size_t)v * 16);
            async_load16(Bt + (size_t)(n0 + row) * K + kt + c * 8, (char*)Bs + (size_t)v * 16);
        }
        __syncthreads();
#pragma unroll
        for (int kk = 0; kk < 64; kk += 32) {
            bf16x8 am[4], bn[4];
#pragma unroll
            for (int i = 0; i < 4; i++) {
                int row = wm * 64 + i * 16 + l15;
                int ch = ((kk >> 3) + quad) ^ (row & 7);
                am[i] = *(const bf16x8*)&As[row * 64 + ch * 8];
            }
#pragma unroll
            for (int j = 0; j < 4; j++) {
                int row = wn * 64 + j * 16 + l15;
                int ch = ((kk >> 3) + quad) ^ (row & 7);
                bn[j] = *(const bf16x8*)&Bs[row * 64 + ch * 8];
            }
#pragma unroll
            for (int i = 0; i < 4; i++)
#pragma unroll
                for (int j = 0; j < 4; j++)
                    acc[i][j] = __builtin_amdgcn_mfma_f32_16x16x32_bf16(am[i], bn[j], acc[i][j], 0, 0, 0);
        }
        __syncthreads();
    }

    if (EPI == 1) {
#pragma unroll
        for (int i = 0; i < 4; i++)
#pragma unroll
            for (int j = 0; j < 4; j++)
#pragma unroll
                for (int r = 0; r < 4; r++) {
                    int mg = m0 + wm * 64 + i * 16 + quad * 4 + r;
                    int ng = n0 + wn * 64 + j * 16 + l15;
                    Out[(size_t)mg * DMODEL + ng] = acc[i][j][r] + bo[ng];
                }
        return;
    }

    const int sel = n0 >> 10;   // block-uniform
    if (sel < 2) {
#pragma unroll
        for (int i = 0; i < 4; i++)
#pragma unroll
            for (int j = 0; j < 4; j++)
#pragma unroll
                for (int r = 0; r < 4; r++) {
                    int mg = m0 + wm * 64 + i * 16 + quad * 4 + r;
                    int ng = n0 + wn * 64 + j * 16 + l15;
                    int h = (ng & 1023) >> 6, d = ng & 63;
                    int b = mg >> 11, s = mg & 2047;
                    size_t idx = ((size_t)((b * NHEAD + h) * SEQ) + s) * HDIM + d;
                    float v = acc[i][j][r];
                    if (sel == 0) Qb[idx] = (bf16_t)(v * QSCALE);
                    else          Kb[idx] = (bf16_t)v;
                }
    } else {
        // V block: in-LDS 128x128 transpose, then coalesced Vt[B,H,64,S] write
        bf16_t* T = smem;  // (nl, ml) at nl*128 + ((ml>>2)^(nl&31))*4 + (ml&3)
#pragma unroll
        for (int i = 0; i < 4; i++)
#pragma unroll
            for (int j = 0; j < 4; j++) {
                int nl = wn * 64 + j * 16 + l15;
                int mlc = wm * 16 + i * 4 + quad;
                bf16x4 p;
#pragma unroll
                for (int r = 0; r < 4; r++) p[r] = (bf16_t)acc[i][j][r];
                *(bf16x4*)&T[nl * 128 + ((mlc ^ (nl & 31)) << 2)] = p;
            }
        __syncthreads();
        const int h0 = (n0 & 1023) >> 6;
        const int b = m0 >> 11, sbase = m0 & 2047;
#pragma unroll
        for (int it = 0; it < 8; it++) {
            int idx = tid + it * 256;
            int nl = idx >> 4, sc = idx & 15;
            bf16x4 lo = *(const bf16x4*)&T[nl * 128 + (((2 * sc) ^ (nl & 31)) << 2)];
            bf16x4 hi = *(const bf16x4*)&T[nl * 128 + (((2 * sc + 1) ^ (nl & 31)) << 2)];
            bf16x8 w;
#pragma unroll
            for (int e = 0; e < 4; e++) { w[e] = lo[e]; w[e + 4] = hi[e]; }
            int h = h0 + (nl >> 6), d = nl & 63;
            *(bf16x8*)(Vt + ((size_t)(b * NHEAD + h) * HDIM + d) * SEQ + sbase + sc * 8) = w;
        }
    }
}

// ---------------------------------------------------------------------------
// Attention v6: 256 thr / 4 waves; each wave owns TWO 16-row q-strips (32 q),
// so each K/V LDS fragment read feeds two MFMAs (K/V+P reads per 128 q drop
// 144 -> 80 b128/tile). Block = 128 q (2 tiles), stages 10 K/V tiles in
// double-buffered LDS. Identity task mapping. exp2 softmax (scale folded into
// Q); denominator via ones-MFMA row-sum. LDS 50 KB -> 3 blocks/CU.
// ---------------------------------------------------------------------------
__global__ __launch_bounds__(256) void attn_kernel(
    const bf16_t* __restrict__ Qb, const bf16_t* __restrict__ Kb,
    const bf16_t* __restrict__ Vt, bf16_t* __restrict__ ctx) {
    __shared__ __attribute__((aligned(16))) bf16_t Ks[2][64 * 64];
    __shared__ __attribute__((aligned(16))) bf16_t Vs[2][64 * 64];
    __shared__ __attribute__((aligned(16))) bf16_t Plds[4][2][16][72];
    const int tid = threadIdx.x;
    const int wave = tid >> 6, lane = tid & 63, quad = lane >> 4, l15 = lane & 15;

    const int id = blockIdx.x;                 // id = b(1) | h(4) | qpair(4)
    const int b = id >> 8, h = (id >> 4) & 15, Q0 = (id & 15) << 7;
    const int qb = Q0 + wave * 32;             // wave's 32-row q-range
    const int wqt = (Q0 >> 6) + (wave >> 1);   // wave's 64-aligned q-tile

    const bf16_t* Qp = Qb + (size_t)(b * NHEAD + h) * SEQ * HDIM;
    const bf16_t* Kp = Kb + (size_t)(b * NHEAD + h) * SEQ * HDIM;
    const bf16_t* Vp = Vt + (size_t)(b * NHEAD + h) * HDIM * SEQ;

    bf16x8 qa[2][2];
#pragma unroll
    for (int ss = 0; ss < 2; ss++) {
        const bf16_t* qr = Qp + (size_t)(qb + ss * 16 + l15) * HDIM;
        qa[ss][0] = *(const bf16x8*)(qr + quad * 8);
        qa[ss][1] = *(const bf16x8*)(qr + 32 + quad * 8);
    }

    bf16x8 ones;
#pragma unroll
    for (int j = 0; j < 8; j++) ones[j] = (bf16_t)1.0f;

    f32x4 O[2][4] = {};
    f32x4 lacc[2] = {};

    const int base_t = Q0 >> 6;
    const int bt0 = (base_t - 4 > 0) ? base_t - 4 : 0;
    const int bt1 = (base_t + 5 < SEQ / 64 - 1) ? base_t + 5 : SEQ / 64 - 1;

    auto stage = [&](int kt, int buf) {
        const int k0 = kt * 64;
#pragma unroll
        for (int i = 0; i < 2; i++) {
            int v = tid + i * 256;             // 512 chunks of 16B each
            int row = v >> 3, c = (v & 7) ^ (row & 7);
            async_load16(Kp + (size_t)(k0 + row) * HDIM + c * 8, (char*)&Ks[buf][0] + (size_t)v * 16);
            async_load16(Vp + (size_t)row * SEQ + k0 + c * 8, (char*)&Vs[buf][0] + (size_t)v * 16);
        }
    };

    stage(bt0, 0);
    int cb = 0;
    for (int kt = bt0; kt <= bt1; kt++) {
        __syncthreads();                       // current tile staged
        if (kt < bt1) stage(kt + 1, cb ^ 1);   // prefetch next during compute
        const int dt = kt - wqt;
        if (dt >= -4 && dt <= 4) {             // wave-uniform window check
            const int k0 = kt * 64;
            f32x4 s[2][4];
#pragma unroll
            for (int c = 0; c < 4; c++) {
                int row = c * 16 + l15;
                bf16x8 kb0 = *(const bf16x8*)&Ks[cb][row * 64 + (quad ^ (row & 7)) * 8];
                bf16x8 kb1 = *(const bf16x8*)&Ks[cb][row * 64 + ((quad + 4) ^ (row & 7)) * 8];
#pragma unroll
                for (int ss = 0; ss < 2; ss++) {
                    f32x4 a = {};
                    a = __builtin_amdgcn_mfma_f32_16x16x32_bf16(qa[ss][0], kb0, a, 0, 0, 0);
                    a = __builtin_amdgcn_mfma_f32_16x16x32_bf16(qa[ss][1], kb1, a, 0, 0, 0);
                    s[ss][c] = a;
                }
            }
            const bool edge = (dt == -4 || dt == 4);
#pragma unroll
            for (int ss = 0; ss < 2; ss++)
#pragma unroll
                for (int c = 0; c < 4; c++)
#pragma unroll
                    for (int r = 0; r < 4; r++) {
                        float sv = s[ss][c][r];
                        if (edge) {
                            int i = qb + ss * 16 + quad * 4 + r;
                            int j = k0 + c * 16 + l15;
                            int dd = i - j; dd = (dd < 0) ? -dd : dd;
                            if (dd > WIN) sv = -1e30f;
                        }
                        Plds[wave][ss][quad * 4 + r][c * 16 + l15] = (bf16_t)__builtin_exp2f(sv);
                    }
            bf16x8 pa[2][2];
#pragma unroll
            for (int ss = 0; ss < 2; ss++) {
                pa[ss][0] = *(const bf16x8*)&Plds[wave][ss][l15][quad * 8];
                pa[ss][1] = *(const bf16x8*)&Plds[wave][ss][l15][32 + quad * 8];
                lacc[ss] = __builtin_amdgcn_mfma_f32_16x16x32_bf16(pa[ss][0], ones, lacc[ss], 0, 0, 0);
                lacc[ss] = __builtin_amdgcn_mfma_f32_16x16x32_bf16(pa[ss][1], ones, lacc[ss], 0, 0, 0);
            }
#pragma unroll
            for (int d = 0; d < 4; d++) {
                int row = d * 16 + l15;
                bf16x8 vb0 = *(const bf16x8*)&Vs[cb][row * 64 + (quad ^ (row & 7)) * 8];
                bf16x8 vb1 = *(const bf16x8*)&Vs[cb][row * 64 + ((quad + 4) ^ (row & 7)) * 8];
#pragma unroll
                for (int ss = 0; ss < 2; ss++) {
                    O[ss][d] = __builtin_amdgcn_mfma_f32_16x16x32_bf16(pa[ss][0], vb0, O[ss][d], 0, 0, 0);
                    O[ss][d] = __builtin_amdgcn_mfma_f32_16x16x32_bf16(pa[ss][1], vb1, O[ss][d], 0, 0, 0);
                }
            }
        }
        __syncthreads();                       // all waves done with cb before reuse
        cb ^= 1;
    }

#pragma unroll
    for (int ss = 0; ss < 2; ss++)
#pragma unroll
        for (int r = 0; r < 4; r++) {
            float inv = 1.0f / lacc[ss][r];
            int i = qb + ss * 16 + quad * 4 + r;
#pragma unroll
            for (int d = 0; d < 4; d++) {
                float v = O[ss][d][r] * inv;
                ctx[((size_t)(b * SEQ + i)) * DMODEL + h * HDIM + d * 16 + l15] = (bf16_t)v;
            }
        }
}

// ---------------------------------------------------------------------------
extern "C" void kernel_launch(void* const* d_in, const int* in_sizes, int n_in,
                              void* d_out, int out_size, void* d_ws, size_t ws_size,
                              hipStream_t stream) {
    const float* x  = (const float*)d_in[0];
    const float* Wq = (const float*)d_in[1];
    const float* Wk = (const float*)d_in[2];
    const float* Wv = (const float*)d_in[3];
    const float* Wo = (const float*)d_in[4];
    const float* bo = (const float*)d_in[5];
    float* out = (float*)d_out;

    const size_t MTOK = (size_t)BATCH * SEQ;          // 4096
    bf16_t* xb  = (bf16_t*)d_ws;                      // 4096*1024
    bf16_t* Wt  = xb + MTOK * DMODEL;                 // 4*1024*1024
    bf16_t* Qb  = Wt + (size_t)4 * DMODEL * DMODEL;   // [B,H,S,64]
    bf16_t* Kb  = Qb + MTOK * DMODEL;                 // [B,H,S,64]
    bf16_t* Vt  = Kb + MTOK * DMODEL;                 // [B,H,64,S]
    bf16_t* ctx = Vt + MTOK * DMODEL;                 // [4096][1024]

    prep_kernel<<<dim3(32, 32, 8), dim3(32, 8), 0, stream>>>(x, Wq, Wk, Wv, Wo, xb, Wt);
    // QKV: M=4096, N=3072, K=1024; 768 blocks, 3 n-strips per XCD; fused V-transpose
    gemm_bt_kernel<0><<<dim3(768), dim3(256), 0, stream>>>(
        xb, Wt, Qb, Kb, Vt, nullptr, nullptr, DMODEL, 3);
    attn_kernel<<<dim3(512), dim3(256), 0, stream>>>(Qb, Kb, Vt, ctx);
    // Out: M=4096, N=1024, K=1024; BM=128 -> 256 blocks, 1 n-strip per XCD
    gemm_bt_kernel<1><<<dim3(256), dim3(256), 0, stream>>>(
        ctx, Wt + (size_t)3 * DMODEL * DMODEL, nullptr, nullptr, nullptr, out, bo, DMODEL, 1);
}